// Round 14
// baseline (66.678 us; speedup 1.0000x reference)
//
#include <hip/hip_runtime.h>
#include <math.h>

// Problem dims (fixed by setup_inputs)
#define B_ 4
#define G_ 8
#define D_ 8
#define H_ 256
#define W_ 320
#define N_ 9
constexpr int HW  = H_ * W_;
constexpr int DHW = D_ * HW;
constexpr int BHW = B_ * HW;
constexpr float BN_EPS = 1e-5f;

// fp16 quad per (pixel, depth-pair j): {xn(2j), xn(2j+1), s(2j), s(2j+1)}
typedef _Float16 h2v __attribute__((ext_vector_type(2)));
typedef _Float16 h4v __attribute__((ext_vector_type(4)));
typedef _Float16 h8v __attribute__((ext_vector_type(8)));

// d_ws float layout:
//   [0..127]    fw0[16][8]   (BN-folded layer0 weights)
//   [128..143]  fb0[16]      (BN-folded layer0 bias)
//   [144..271]  fw1[8][16]
//   [272..279]  fb1[8]
//   [280..287]  fw2[8]
//   [288]       fb2
//   [292..295]  sc[B]        (xnorm scale per batch)
//   [296..299]  ofs[B]       (xnorm offset per batch)
//   [320...]    pair planes: h4v plane[4][B*HW]  (10.5 MB)
#define WS_PAIR_OFF 320

// XCD band swizzle: each XCD owns a contiguous pixel band so its plane
// slice stays L2-resident across all 9 neighbor passes.
__device__ __forceinline__ int swz_band(int bid, int per_xcd) {
    return (bid & 7) * per_xcd + (bid >> 3);
}

// ---------------- Kernel 0: fold BN into weights, precompute xnorm affine ----------------
__global__ void k_setup(
    const float* __restrict__ dmin, const float* __restrict__ dmax,
    const float* __restrict__ w0, const float* __restrict__ g0, const float* __restrict__ b0,
    const float* __restrict__ m0, const float* __restrict__ v0,
    const float* __restrict__ w1, const float* __restrict__ g1, const float* __restrict__ b1,
    const float* __restrict__ m1, const float* __restrict__ v1,
    const float* __restrict__ w2, const float* __restrict__ b2,
    float* __restrict__ ws)
{
    int t = threadIdx.x;
    if (t < 16) {
        float inv   = g0[t] * rsqrtf(v0[t] + BN_EPS);
        float shift = b0[t] - m0[t] * inv;
        for (int g = 0; g < G_; ++g) ws[t * G_ + g] = w0[t * G_ + g] * inv;
        ws[128 + t] = shift;
    }
    if (t < 8) {
        float inv   = g1[t] * rsqrtf(v1[t] + BN_EPS);
        float shift = b1[t] - m1[t] * inv;
        for (int i = 0; i < 16; ++i) ws[144 + t * 16 + i] = w1[t * 16 + i] * inv;
        ws[272 + t] = shift;
        ws[280 + t] = w2[t];
    }
    if (t == 0) ws[288] = b2[0];
    if (t < B_) {
        float imin = 1.0f / dmin[t];
        float imax = 1.0f / dmax[t];
        float sc   = 1.0f / (imin - imax);
        ws[292 + t] = sc;
        ws[296 + t] = -imax * sc;
    }
}

// ---------------- MLP for one pixel-depth: G costs -> s ----------------
__device__ __forceinline__ float mlp_eval(const float c[G_], const float* __restrict__ ws) {
    float h0[16];
#pragma unroll
    for (int o = 0; o < 16; ++o) {
        float acc = ws[128 + o];
#pragma unroll
        for (int g = 0; g < G_; ++g) acc = fmaf(c[g], ws[o * G_ + g], acc);
        h0[o] = fmaxf(acc, 0.0f);
    }
    float h1[8];
#pragma unroll
    for (int o = 0; o < 8; ++o) {
        float acc = ws[272 + o];
#pragma unroll
        for (int i = 0; i < 16; ++i) acc = fmaf(h0[i], ws[144 + o * 16 + i], acc);
        h1[o] = fmaxf(acc, 0.0f);
    }
    float s = ws[288];
#pragma unroll
    for (int i = 0; i < 8; ++i) s = fmaf(h1[i], ws[280 + i], s);
    return s;
}

// ---------------- Kernel 1: one thread per (pixel, depth-pair) ----------------
__global__ __launch_bounds__(256) void k_s_xnorm(
    const float* __restrict__ cost,      // [B,G,D,H,W]
    const float* __restrict__ dsamp,     // [B,D,H,W]
    const float* __restrict__ ws,
    h4v* __restrict__ plane)             // [4][B*HW]
{
    int tid = swz_band(blockIdx.x, 640) * 256 + threadIdx.x;  // over B*HW*4
    int j   = tid & 3;
    int idx = tid >> 2;          // b*HW + pix
    int b   = idx / HW;
    int pix = idx % HW;
    int d0  = j * 2;

    float sc  = ws[292 + b];
    float ofs = ws[296 + b];

    const float* cb = cost  + (size_t)b * G_ * DHW + (size_t)d0 * HW + pix;
    const float* db = dsamp + (size_t)b * DHW + (size_t)d0 * HW + pix;

    float c0[G_], c1[G_];
#pragma unroll
    for (int g = 0; g < G_; ++g) {
        c0[g] = cb[(size_t)g * DHW];
        c1[g] = cb[(size_t)g * DHW + HW];
    }

    float s0 = mlp_eval(c0, ws);
    float s1 = mlp_eval(c1, ws);

    float xn0 = fmaf(__builtin_amdgcn_rcpf(db[0]),  sc, ofs);
    float xn1 = fmaf(__builtin_amdgcn_rcpf(db[HW]), sc, ofs);

    // layout: {xn0, xn1, s0, s1}
    h4v res;
    res[0] = (_Float16)xn0;
    res[1] = (_Float16)xn1;
    res[2] = (_Float16)s0;
    res[3] = (_Float16)s1;

    plane[(size_t)j * BHW + idx] = res;
}

__device__ __forceinline__ h4v lo4(h8v r) { h4v o; o[0]=r[0]; o[1]=r[1]; o[2]=r[2]; o[3]=r[3]; return o; }
__device__ __forceinline__ h4v hi4(h8v r) { h4v o; o[0]=r[4]; o[1]=r[5]; o[2]=r[6]; o[3]=r[7]; return o; }

// ---- gather + kernel-weight + accumulate for one pixel, one neighbor ----
__device__ __forceinline__ void neighbor_accum(
    const h4v* __restrict__ plane, int bbase, float2 g, float fw,
    const h2v xnc2[4], float acc[D_],
    h2v c0v, h2v c1v, h2v c2v, h2v c3v, h2v n40, h2v two, h2v ntwo, h2v halfv)
{
    // align_corners=False, border padding
    float gxp = fminf(fmaxf((g.x + 1.0f) * 0.5f * W_ - 0.5f, 0.0f), (float)(W_ - 1));
    float gyp = fminf(fmaxf((g.y + 1.0f) * 0.5f * H_ - 0.5f, 0.0f), (float)(H_ - 1));
    float x0f = floorf(gxp);
    float y0f = floorf(gyp);
    float wx = gxp - x0f;          // == 0 exactly when x0 == W-1 (clamped)
    float wy = gyp - y0f;
    int x0 = (int)x0f;
    int y0 = (int)y0f;
    int y1 = min(y0 + 1, H_ - 1);

    _Float16 wxh = (_Float16)wx;
    _Float16 wyh = (_Float16)wy;
    h4v wxv = {wxh, wxh, wxh, wxh};
    h4v wyv = {wyh, wyh, wyh, wyh};

    int oA = bbase + y0 * W_ + x0;  // row y0: pixels x0 & x0+1 via one 16B load
    int oB = bbase + y1 * W_ + x0;  // row y1

#pragma unroll
    for (int j = 0; j < 4; ++j) {
        const h4v* pj = plane + (size_t)j * BHW;
        h8v rA = *(const h8v*)(pj + oA);
        h8v rB = *(const h8v*)(pj + oB);

        h4v tA = lo4(rA), uA = hi4(rA);
        h4v tB = lo4(rB), uB = hi4(rB);

        // packed fp16 bilinear: x-lerp both rows, then y-lerp
        h4v ax = tA + wxv * (uA - tA);
        h4v bx = tB + wxv * (uB - tB);
        h4v cy = ax + wyv * (bx - ax);   // {xs0, xs1, ss0, ss1}

        h2v xs2; xs2[0] = cy[0]; xs2[1] = cy[1];
        h2v ss2; ss2[0] = cy[2]; ss2[1] = cy[3];

        // dw = 0.5 + y*P(y^2), y = max(2 - 40|xs-xnc|, -2)
        h2v del  = xs2 - xnc2[j];
        h2v absd = __builtin_elementwise_max(del, -del);
        h2v y2   = __builtin_elementwise_max(two + n40 * absd, ntwo);
        h2v u2   = y2 * y2;
        h2v P    = c2v + u2 * c3v;
        P        = c1v + u2 * P;
        P        = c0v + u2 * P;
        h2v dw2  = halfv + y2 * P;
        h2v pr   = dw2 * ss2;

        acc[2 * j]     = fmaf((float)pr[0], fw, acc[2 * j]);
        acc[2 * j + 1] = fmaf((float)pr[1], fw, acc[2 * j + 1]);
    }
}

// ---------------- Kernel 2: neighbor gather + sigmoid kernel + aggregate ----------------
// TWO pixels per thread: (row hA, col wq) and (row hA+64, col wq), both inside
// the same 128-row XCD band (band k = rows [128k, 128k+128) = exactly what
// k1's XCD k produced). Two fully independent gather/compute chains per
// thread -> ~2x in-flight VMEM, so L1/L2 latency overlaps the VALU work.
// Every load instruction stays single-row coalesced.
__global__ __launch_bounds__(256) void k_aggregate(
    const float* __restrict__ grid,      // [B, N*H, W, 2]
    const float* __restrict__ fweight,   // [B, N, H, W]
    const h4v* __restrict__ plane,       // [4][B*HW]
    float* __restrict__ out)             // [B,D,H,W]
{
    int idx  = swz_band(blockIdx.x, 80) * 256 + threadIdx.x;  // over B*H*W/2
    int band = idx / (64 * W_);          // 0..7: 128-row band (XCD affinity)
    int rem  = idx % (64 * W_);
    int hh   = rem / W_;                 // 0..63 within band
    int wq   = rem % W_;

    int RA = band * 128 + hh;            // global row index over b*H+h, half A
    int b  = RA / H_;
    int hA = RA % H_;
    int hB = hA + 64;                    // half B row (same b, same band)

    int idxA = RA * W_ + wq;             // = b*HW + hA*W + wq
    int idxB = idxA + 64 * W_;

    const float2* gp = (const float2*)grid;
    const float2* gpA = gp + ((size_t)b * (N_ * H_) + hA) * W_ + wq;
    const float2* gpB = gp + ((size_t)b * (N_ * H_) + hB) * W_ + wq;
    const float*  fpA = fweight + (size_t)b * N_ * HW + (size_t)hA * W_ + wq;
    const float*  fpB = fweight + (size_t)b * N_ * HW + (size_t)hB * W_ + wq;

    // ---- center xnorm pairs ----
    h2v xncA[4], xncB[4];
#pragma unroll
    for (int j = 0; j < 4; ++j) {
        h4v vA = plane[(size_t)j * BHW + idxA];
        h4v vB = plane[(size_t)j * BHW + idxB];
        h2v pA; pA[0] = vA[0]; pA[1] = vA[1]; xncA[j] = pA;
        h2v pB; pB[0] = vB[0]; pB[1] = vB[1]; xncB[j] = pB;
    }

    float accA[D_], accB[D_];
#pragma unroll
    for (int d = 0; d < D_; ++d) { accA[d] = 0.0f; accB[d] = 0.0f; }

    const int bbase = b * HW;

    const _Float16 kC0 = (_Float16)0.4974878f;
    const _Float16 kC1 = (_Float16)(-0.1454196f);
    const _Float16 kC2 = (_Float16)0.0327724f;
    const _Float16 kC3 = (_Float16)(-0.0031269f);
    const h2v c0v = {kC0, kC0};
    const h2v c1v = {kC1, kC1};
    const h2v c2v = {kC2, kC2};
    const h2v c3v = {kC3, kC3};
    const h2v n40 = {(_Float16)(-40.0f), (_Float16)(-40.0f)};
    const h2v two = {(_Float16)2.0f, (_Float16)2.0f};
    const h2v ntwo = {(_Float16)(-2.0f), (_Float16)(-2.0f)};
    const h2v halfv = {(_Float16)0.5f, (_Float16)0.5f};

#pragma unroll
    for (int n = 0; n < N_; ++n) {
        float2 gA  = gpA[(size_t)n * (H_ * W_)];
        float2 gB  = gpB[(size_t)n * (H_ * W_)];
        float  fwA = fpA[(size_t)n * HW];
        float  fwB = fpB[(size_t)n * HW];

        neighbor_accum(plane, bbase, gA, fwA, xncA, accA,
                       c0v, c1v, c2v, c3v, n40, two, ntwo, halfv);
        neighbor_accum(plane, bbase, gB, fwB, xncB, accB,
                       c0v, c1v, c2v, c3v, n40, two, ntwo, halfv);
    }

#pragma unroll
    for (int d = 0; d < D_; ++d) {
        out[(b * D_ + d) * HW + (size_t)hA * W_ + wq] = accA[d];
        out[(b * D_ + d) * HW + (size_t)hB * W_ + wq] = accB[d];
    }
}

extern "C" void kernel_launch(void* const* d_in, const int* in_sizes, int n_in,
                              void* d_out, int out_size, void* d_ws, size_t ws_size,
                              hipStream_t stream) {
    const float* cost    = (const float*)d_in[0];
    const float* dsamp   = (const float*)d_in[1];
    const float* dmin    = (const float*)d_in[2];
    const float* dmax    = (const float*)d_in[3];
    const float* grid    = (const float*)d_in[4];
    const float* fweight = (const float*)d_in[5];
    const float* w0 = (const float*)d_in[6];
    const float* g0 = (const float*)d_in[7];
    const float* b0 = (const float*)d_in[8];
    const float* m0 = (const float*)d_in[9];
    const float* v0 = (const float*)d_in[10];
    const float* w1 = (const float*)d_in[11];
    const float* g1 = (const float*)d_in[12];
    const float* b1 = (const float*)d_in[13];
    const float* m1 = (const float*)d_in[14];
    const float* v1 = (const float*)d_in[15];
    const float* w2 = (const float*)d_in[16];
    const float* b2 = (const float*)d_in[17];
    float* out = (float*)d_out;

    float* ws    = (float*)d_ws;
    h4v*   plane = (h4v*)(ws + WS_PAIR_OFF);

    k_setup<<<1, 64, 0, stream>>>(dmin, dmax,
                                  w0, g0, b0, m0, v0,
                                  w1, g1, b1, m1, v1,
                                  w2, b2, ws);

    // k1: 5120 blocks over (pixel, depth-pair); k2: 640 blocks over
    // (band, row-in-half, col) pairs. Both map pixel p -> XCD p/40960.
    k_s_xnorm<<<5120, 256, 0, stream>>>(cost, dsamp, ws, plane);
    k_aggregate<<<640, 256, 0, stream>>>(grid, fweight, plane, out);
}

// Round 15
// 58.947 us; speedup vs baseline: 1.1312x; 1.1312x over previous
//
#include <hip/hip_runtime.h>
#include <math.h>

// Problem dims (fixed by setup_inputs)
#define B_ 4
#define G_ 8
#define D_ 8
#define H_ 256
#define W_ 320
#define N_ 9
constexpr int HW  = H_ * W_;
constexpr int DHW = D_ * HW;
constexpr int BHW = B_ * HW;
constexpr float BN_EPS = 1e-5f;

// fp16 quad per (pixel, depth-pair j): {xn(2j), xn(2j+1), s(2j), s(2j+1)}
typedef _Float16 h2v __attribute__((ext_vector_type(2)));
typedef _Float16 h4v __attribute__((ext_vector_type(4)));
typedef _Float16 h8v __attribute__((ext_vector_type(8)));

// d_ws float layout:
//   [0..127]    fw0[16][8]   (BN-folded layer0 weights)
//   [128..143]  fb0[16]      (BN-folded layer0 bias)
//   [144..271]  fw1[8][16]
//   [272..279]  fb1[8]
//   [280..287]  fw2[8]
//   [288]       fb2
//   [292..295]  sc[B]        (xnorm scale per batch)
//   [296..299]  ofs[B]       (xnorm offset per batch)
//   [320...]    pair planes: h4v plane[4][B*HW]  (10.5 MB)
#define WS_PAIR_OFF 320

// XCD band swizzle: each XCD owns a contiguous pixel band so its plane
// slice stays L2-resident across all 9 neighbor passes.
__device__ __forceinline__ int swz_band(int bid, int per_xcd) {
    return (bid & 7) * per_xcd + (bid >> 3);
}

// ---------------- Kernel 0: fold BN into weights, precompute xnorm affine ----------------
__global__ void k_setup(
    const float* __restrict__ dmin, const float* __restrict__ dmax,
    const float* __restrict__ w0, const float* __restrict__ g0, const float* __restrict__ b0,
    const float* __restrict__ m0, const float* __restrict__ v0,
    const float* __restrict__ w1, const float* __restrict__ g1, const float* __restrict__ b1,
    const float* __restrict__ m1, const float* __restrict__ v1,
    const float* __restrict__ w2, const float* __restrict__ b2,
    float* __restrict__ ws)
{
    int t = threadIdx.x;
    if (t < 16) {
        float inv   = g0[t] * rsqrtf(v0[t] + BN_EPS);
        float shift = b0[t] - m0[t] * inv;
        for (int g = 0; g < G_; ++g) ws[t * G_ + g] = w0[t * G_ + g] * inv;
        ws[128 + t] = shift;
    }
    if (t < 8) {
        float inv   = g1[t] * rsqrtf(v1[t] + BN_EPS);
        float shift = b1[t] - m1[t] * inv;
        for (int i = 0; i < 16; ++i) ws[144 + t * 16 + i] = w1[t * 16 + i] * inv;
        ws[272 + t] = shift;
        ws[280 + t] = w2[t];
    }
    if (t == 0) ws[288] = b2[0];
    if (t < B_) {
        float imin = 1.0f / dmin[t];
        float imax = 1.0f / dmax[t];
        float sc   = 1.0f / (imin - imax);
        ws[292 + t] = sc;
        ws[296 + t] = -imax * sc;
    }
}

// ---------------- MLP for one pixel-depth: G costs -> s ----------------
__device__ __forceinline__ float mlp_eval(const float c[G_], const float* __restrict__ ws) {
    float h0[16];
#pragma unroll
    for (int o = 0; o < 16; ++o) {
        float acc = ws[128 + o];
#pragma unroll
        for (int g = 0; g < G_; ++g) acc = fmaf(c[g], ws[o * G_ + g], acc);
        h0[o] = fmaxf(acc, 0.0f);
    }
    float h1[8];
#pragma unroll
    for (int o = 0; o < 8; ++o) {
        float acc = ws[272 + o];
#pragma unroll
        for (int i = 0; i < 16; ++i) acc = fmaf(h0[i], ws[144 + o * 16 + i], acc);
        h1[o] = fmaxf(acc, 0.0f);
    }
    float s = ws[288];
#pragma unroll
    for (int i = 0; i < 8; ++i) s = fmaf(h1[i], ws[280 + i], s);
    return s;
}

// ---------------- Kernel 1: one thread per (pixel, depth-pair) ----------------
__global__ __launch_bounds__(256) void k_s_xnorm(
    const float* __restrict__ cost,      // [B,G,D,H,W]
    const float* __restrict__ dsamp,     // [B,D,H,W]
    const float* __restrict__ ws,
    h4v* __restrict__ plane)             // [4][B*HW]
{
    int tid = swz_band(blockIdx.x, 640) * 256 + threadIdx.x;  // over B*HW*4
    int j   = tid & 3;
    int idx = tid >> 2;          // b*HW + pix
    int b   = idx / HW;
    int pix = idx % HW;
    int d0  = j * 2;

    float sc  = ws[292 + b];
    float ofs = ws[296 + b];

    const float* cb = cost  + (size_t)b * G_ * DHW + (size_t)d0 * HW + pix;
    const float* db = dsamp + (size_t)b * DHW + (size_t)d0 * HW + pix;

    float c0[G_], c1[G_];
#pragma unroll
    for (int g = 0; g < G_; ++g) {
        c0[g] = cb[(size_t)g * DHW];
        c1[g] = cb[(size_t)g * DHW + HW];
    }

    float s0 = mlp_eval(c0, ws);
    float s1 = mlp_eval(c1, ws);

    float xn0 = fmaf(__builtin_amdgcn_rcpf(db[0]),  sc, ofs);
    float xn1 = fmaf(__builtin_amdgcn_rcpf(db[HW]), sc, ofs);

    // layout: {xn0, xn1, s0, s1}
    h4v res;
    res[0] = (_Float16)xn0;
    res[1] = (_Float16)xn1;
    res[2] = (_Float16)s0;
    res[3] = (_Float16)s1;

    plane[(size_t)j * BHW + idx] = res;
}

__device__ __forceinline__ h4v lo4(h8v r) { h4v o; o[0]=r[0]; o[1]=r[1]; o[2]=r[2]; o[3]=r[3]; return o; }
__device__ __forceinline__ h4v hi4(h8v r) { h4v o; o[0]=r[4]; o[1]=r[5]; o[2]=r[6]; o[3]=r[7]; return o; }

// ---------------- Kernel 2: neighbor gather + sigmoid kernel + aggregate ----------------
// 1 thread per pixel, all 8 depths, SOFTWARE-PIPELINED over 9 neighbors:
//   stage A: all 9 grid+fw loads (18 independent) -> coords in registers
//   stage B: double-buffered tap loads — issue neighbor n+1's 8 taps before
//            consuming neighbor n (parity-indexed reg arrays, all indices
//            compile-time) -> per-neighbor time = max(VALU, load), not sum.
// __launch_bounds__(256, 2): explicit 256-VGPR budget so the allocator keeps
// ~64 VGPRs of in-flight tap data (round-14 showed default heuristics pick
// VGPR=32 and serialize the chains).
__global__ __launch_bounds__(256, 2) void k_aggregate(
    const float* __restrict__ grid,      // [B, N*H, W, 2]
    const float* __restrict__ fweight,   // [B, N, H, W]
    const h4v* __restrict__ plane,       // [4][B*HW]
    float* __restrict__ out)             // [B,D,H,W]
{
    int idx = swz_band(blockIdx.x, 160) * 256 + threadIdx.x;  // b*HW + pix
    int b   = idx / HW;
    int pix = idx % HW;
    int h   = pix / W_;
    int wq  = pix % W_;

    const float2* gpx = (const float2*)grid + (size_t)b * (N_ * H_) * W_ + (size_t)h * W_ + wq;
    const float*  fpx = fweight + (size_t)b * N_ * HW + (size_t)h * W_ + wq;

    // ---- center xnorm pair per plane ----
    h2v xnc2[4];
#pragma unroll
    for (int j = 0; j < 4; ++j) {
        h4v v = plane[(size_t)j * BHW + idx];
        h2v p; p[0] = v[0]; p[1] = v[1];
        xnc2[j] = p;
    }

    float acc[D_];
#pragma unroll
    for (int d = 0; d < D_; ++d) acc[d] = 0.0f;

    const int bbase = b * HW;

    const _Float16 kC0 = (_Float16)0.4974878f;
    const _Float16 kC1 = (_Float16)(-0.1454196f);
    const _Float16 kC2 = (_Float16)0.0327724f;
    const _Float16 kC3 = (_Float16)(-0.0031269f);
    const h2v c0v = {kC0, kC0};
    const h2v c1v = {kC1, kC1};
    const h2v c2v = {kC2, kC2};
    const h2v c3v = {kC3, kC3};
    const h2v n40 = {(_Float16)(-40.0f), (_Float16)(-40.0f)};
    const h2v two = {(_Float16)2.0f, (_Float16)2.0f};
    const h2v ntwo = {(_Float16)(-2.0f), (_Float16)(-2.0f)};
    const h2v halfv = {(_Float16)0.5f, (_Float16)0.5f};

    // ---- stage A: all 9 coords from 18 independent loads ----
    int   oAv[N_], oBv[N_];
    h4v   wxv[N_], wyv[N_];
    float fwv[N_];
#pragma unroll
    for (int n = 0; n < N_; ++n) {
        float2 g  = gpx[(size_t)n * (H_ * W_)];
        fwv[n]    = fpx[(size_t)n * HW];

        float gxp = fminf(fmaxf((g.x + 1.0f) * 0.5f * W_ - 0.5f, 0.0f), (float)(W_ - 1));
        float gyp = fminf(fmaxf((g.y + 1.0f) * 0.5f * H_ - 0.5f, 0.0f), (float)(H_ - 1));
        float x0f = floorf(gxp);
        float y0f = floorf(gyp);
        float wx = gxp - x0f;          // == 0 exactly when x0 == W-1 (clamped)
        float wy = gyp - y0f;
        int x0 = (int)x0f;
        int y0 = (int)y0f;
        int y1 = min(y0 + 1, H_ - 1);

        _Float16 wxh = (_Float16)wx;
        _Float16 wyh = (_Float16)wy;
        h4v wv = {wxh, wxh, wxh, wxh};
        h4v yv = {wyh, wyh, wyh, wyh};
        wxv[n] = wv;
        wyv[n] = yv;
        oAv[n] = bbase + y0 * W_ + x0;
        oBv[n] = bbase + y1 * W_ + x0;
    }

    // ---- stage B: double-buffered taps ----
    h8v rA[2][4], rB[2][4];
#pragma unroll
    for (int j = 0; j < 4; ++j) {
        const h4v* pj = plane + (size_t)j * BHW;
        rA[0][j] = *(const h8v*)(pj + oAv[0]);
        rB[0][j] = *(const h8v*)(pj + oBv[0]);
    }

#pragma unroll
    for (int n = 0; n < N_; ++n) {
        const int cur = n & 1;
        const int nxt = cur ^ 1;
        if (n + 1 < N_) {
#pragma unroll
            for (int j = 0; j < 4; ++j) {
                const h4v* pj = plane + (size_t)j * BHW;
                rA[nxt][j] = *(const h8v*)(pj + oAv[n + 1]);
                rB[nxt][j] = *(const h8v*)(pj + oBv[n + 1]);
            }
        }

        float fw = fwv[n];
#pragma unroll
        for (int j = 0; j < 4; ++j) {
            h8v ra = rA[cur][j];
            h8v rb = rB[cur][j];

            h4v tA = lo4(ra), uA = hi4(ra);
            h4v tB = lo4(rb), uB = hi4(rb);

            // packed fp16 bilinear: x-lerp both rows, then y-lerp
            h4v ax = tA + wxv[n] * (uA - tA);
            h4v bx = tB + wxv[n] * (uB - tB);
            h4v cy = ax + wyv[n] * (bx - ax);   // {xs0, xs1, ss0, ss1}

            h2v xs2; xs2[0] = cy[0]; xs2[1] = cy[1];
            h2v ss2; ss2[0] = cy[2]; ss2[1] = cy[3];

            // dw = 0.5 + y*P(y^2), y = max(2 - 40|xs-xnc|, -2)
            h2v del  = xs2 - xnc2[j];
            h2v absd = __builtin_elementwise_max(del, -del);
            h2v y2   = __builtin_elementwise_max(two + n40 * absd, ntwo);
            h2v u2   = y2 * y2;
            h2v P    = c2v + u2 * c3v;
            P        = c1v + u2 * P;
            P        = c0v + u2 * P;
            h2v dw2  = halfv + y2 * P;
            h2v pr   = dw2 * ss2;

            acc[2 * j]     = fmaf((float)pr[0], fw, acc[2 * j]);
            acc[2 * j + 1] = fmaf((float)pr[1], fw, acc[2 * j + 1]);
        }
    }

#pragma unroll
    for (int d = 0; d < D_; ++d) out[(b * D_ + d) * HW + pix] = acc[d];
}

extern "C" void kernel_launch(void* const* d_in, const int* in_sizes, int n_in,
                              void* d_out, int out_size, void* d_ws, size_t ws_size,
                              hipStream_t stream) {
    const float* cost    = (const float*)d_in[0];
    const float* dsamp   = (const float*)d_in[1];
    const float* dmin    = (const float*)d_in[2];
    const float* dmax    = (const float*)d_in[3];
    const float* grid    = (const float*)d_in[4];
    const float* fweight = (const float*)d_in[5];
    const float* w0 = (const float*)d_in[6];
    const float* g0 = (const float*)d_in[7];
    const float* b0 = (const float*)d_in[8];
    const float* m0 = (const float*)d_in[9];
    const float* v0 = (const float*)d_in[10];
    const float* w1 = (const float*)d_in[11];
    const float* g1 = (const float*)d_in[12];
    const float* b1 = (const float*)d_in[13];
    const float* m1 = (const float*)d_in[14];
    const float* v1 = (const float*)d_in[15];
    const float* w2 = (const float*)d_in[16];
    const float* b2 = (const float*)d_in[17];
    float* out = (float*)d_out;

    float* ws    = (float*)d_ws;
    h4v*   plane = (h4v*)(ws + WS_PAIR_OFF);

    k_setup<<<1, 64, 0, stream>>>(dmin, dmax,
                                  w0, g0, b0, m0, v0,
                                  w1, g1, b1, m1, v1,
                                  w2, b2, ws);

    // k1: 5120 blocks over (pixel, depth-pair); k2: 1280 blocks over pixels.
    // Both map pixel p -> XCD p/40960 (producer/consumer L2 affinity).
    k_s_xnorm<<<5120, 256, 0, stream>>>(cost, dsamp, ws, plane);
    k_aggregate<<<1280, 256, 0, stream>>>(grid, fweight, plane, out);
}

// Round 17
// 52.009 us; speedup vs baseline: 1.2821x; 1.1334x over previous
//
#include <hip/hip_runtime.h>
#include <math.h>

// Problem dims (fixed by setup_inputs)
#define B_ 4
#define G_ 8
#define D_ 8
#define H_ 256
#define W_ 320
#define N_ 9
constexpr int HW  = H_ * W_;
constexpr int DHW = D_ * HW;
constexpr int BHW = B_ * HW;
constexpr float BN_EPS = 1e-5f;

// fp16 quad per (pixel, depth-pair j): {xn(2j), xn(2j+1), s(2j), s(2j+1)}
typedef _Float16 h2v __attribute__((ext_vector_type(2)));
typedef _Float16 h4v __attribute__((ext_vector_type(4)));
typedef _Float16 h8v __attribute__((ext_vector_type(8)));

// d_ws float layout:
//   [0..127]    fw0[16][8]   (BN-folded layer0 weights)
//   [128..143]  fb0[16]      (BN-folded layer0 bias)
//   [144..271]  fw1[8][16]
//   [272..279]  fb1[8]
//   [280..287]  fw2[8]
//   [288]       fb2
//   [292..295]  sc[B]        (xnorm scale per batch)
//   [296..299]  ofs[B]       (xnorm offset per batch)
//   [320...]    pair planes: h4v plane[4][B*HW]  (10.5 MB)
#define WS_PAIR_OFF 320

// XCD band swizzle: each XCD owns a contiguous pixel band so its plane
// slice stays L2-resident across all 9 neighbor passes.
__device__ __forceinline__ int swz_band(int bid, int per_xcd) {
    return (bid & 7) * per_xcd + (bid >> 3);
}

// ---------------- Kernel 0: fold BN into weights, precompute xnorm affine ----------------
__global__ void k_setup(
    const float* __restrict__ dmin, const float* __restrict__ dmax,
    const float* __restrict__ w0, const float* __restrict__ g0, const float* __restrict__ b0,
    const float* __restrict__ m0, const float* __restrict__ v0,
    const float* __restrict__ w1, const float* __restrict__ g1, const float* __restrict__ b1,
    const float* __restrict__ m1, const float* __restrict__ v1,
    const float* __restrict__ w2, const float* __restrict__ b2,
    float* __restrict__ ws)
{
    int t = threadIdx.x;
    if (t < 16) {
        float inv   = g0[t] * rsqrtf(v0[t] + BN_EPS);
        float shift = b0[t] - m0[t] * inv;
        for (int g = 0; g < G_; ++g) ws[t * G_ + g] = w0[t * G_ + g] * inv;
        ws[128 + t] = shift;
    }
    if (t < 8) {
        float inv   = g1[t] * rsqrtf(v1[t] + BN_EPS);
        float shift = b1[t] - m1[t] * inv;
        for (int i = 0; i < 16; ++i) ws[144 + t * 16 + i] = w1[t * 16 + i] * inv;
        ws[272 + t] = shift;
        ws[280 + t] = w2[t];
    }
    if (t == 0) ws[288] = b2[0];
    if (t < B_) {
        float imin = 1.0f / dmin[t];
        float imax = 1.0f / dmax[t];
        float sc   = 1.0f / (imin - imax);
        ws[292 + t] = sc;
        ws[296 + t] = -imax * sc;
    }
}

// ---------------- MLP for one pixel-depth: G costs -> s ----------------
__device__ __forceinline__ float mlp_eval(const float c[G_], const float* __restrict__ ws) {
    float h0[16];
#pragma unroll
    for (int o = 0; o < 16; ++o) {
        float acc = ws[128 + o];
#pragma unroll
        for (int g = 0; g < G_; ++g) acc = fmaf(c[g], ws[o * G_ + g], acc);
        h0[o] = fmaxf(acc, 0.0f);
    }
    float h1[8];
#pragma unroll
    for (int o = 0; o < 8; ++o) {
        float acc = ws[272 + o];
#pragma unroll
        for (int i = 0; i < 16; ++i) acc = fmaf(h0[i], ws[144 + o * 16 + i], acc);
        h1[o] = fmaxf(acc, 0.0f);
    }
    float s = ws[288];
#pragma unroll
    for (int i = 0; i < 8; ++i) s = fmaf(h1[i], ws[280 + i], s);
    return s;
}

// ---------------- Kernel 1: one thread per (pixel, depth-pair) ----------------
__global__ __launch_bounds__(256) void k_s_xnorm(
    const float* __restrict__ cost,      // [B,G,D,H,W]
    const float* __restrict__ dsamp,     // [B,D,H,W]
    const float* __restrict__ ws,
    h4v* __restrict__ plane)             // [4][B*HW]
{
    int tid = swz_band(blockIdx.x, 640) * 256 + threadIdx.x;  // over B*HW*4
    int j   = tid & 3;
    int idx = tid >> 2;          // b*HW + pix
    int b   = idx / HW;
    int pix = idx % HW;
    int d0  = j * 2;

    float sc  = ws[292 + b];
    float ofs = ws[296 + b];

    const float* cb = cost  + (size_t)b * G_ * DHW + (size_t)d0 * HW + pix;
    const float* db = dsamp + (size_t)b * DHW + (size_t)d0 * HW + pix;

    float c0[G_], c1[G_];
#pragma unroll
    for (int g = 0; g < G_; ++g) {
        c0[g] = cb[(size_t)g * DHW];
        c1[g] = cb[(size_t)g * DHW + HW];
    }

    float s0 = mlp_eval(c0, ws);
    float s1 = mlp_eval(c1, ws);

    float xn0 = fmaf(__builtin_amdgcn_rcpf(db[0]),  sc, ofs);
    float xn1 = fmaf(__builtin_amdgcn_rcpf(db[HW]), sc, ofs);

    // layout: {xn0, xn1, s0, s1}
    h4v res;
    res[0] = (_Float16)xn0;
    res[1] = (_Float16)xn1;
    res[2] = (_Float16)s0;
    res[3] = (_Float16)s1;

    plane[(size_t)j * BHW + idx] = res;
}

__device__ __forceinline__ h4v lo4(h8v r) { h4v o; o[0]=r[0]; o[1]=r[1]; o[2]=r[2]; o[3]=r[3]; return o; }
__device__ __forceinline__ h4v hi4(h8v r) { h4v o; o[0]=r[4]; o[1]=r[5]; o[2]=r[6]; o[3]=r[7]; return o; }

// ---- gather + kernel-weight + accumulate for one pixel, one neighbor ----
__device__ __forceinline__ void neighbor_accum(
    const h4v* __restrict__ plane, int bbase, float2 g, float fw,
    const h2v xnc2[4], float acc[D_])
{
    const _Float16 kC0 = (_Float16)0.4974878f;
    const _Float16 kC1 = (_Float16)(-0.1454196f);
    const _Float16 kC2 = (_Float16)0.0327724f;
    const _Float16 kC3 = (_Float16)(-0.0031269f);
    const h2v c0v = {kC0, kC0};
    const h2v c1v = {kC1, kC1};
    const h2v c2v = {kC2, kC2};
    const h2v c3v = {kC3, kC3};
    const h2v n40 = {(_Float16)(-40.0f), (_Float16)(-40.0f)};
    const h2v two = {(_Float16)2.0f, (_Float16)2.0f};
    const h2v ntwo = {(_Float16)(-2.0f), (_Float16)(-2.0f)};
    const h2v halfv = {(_Float16)0.5f, (_Float16)0.5f};

    // align_corners=False, border padding
    float gxp = fminf(fmaxf((g.x + 1.0f) * 0.5f * W_ - 0.5f, 0.0f), (float)(W_ - 1));
    float gyp = fminf(fmaxf((g.y + 1.0f) * 0.5f * H_ - 0.5f, 0.0f), (float)(H_ - 1));
    float x0f = floorf(gxp);
    float y0f = floorf(gyp);
    float wx = gxp - x0f;          // == 0 exactly when x0 == W-1 (clamped)
    float wy = gyp - y0f;
    int x0 = (int)x0f;
    int y0 = (int)y0f;
    int y1 = min(y0 + 1, H_ - 1);

    _Float16 wxh = (_Float16)wx;
    _Float16 wyh = (_Float16)wy;
    h4v wxv = {wxh, wxh, wxh, wxh};
    h4v wyv = {wyh, wyh, wyh, wyh};

    int oA = bbase + y0 * W_ + x0;  // row y0: pixels x0 & x0+1 via one 16B load
    int oB = bbase + y1 * W_ + x0;  // row y1

#pragma unroll
    for (int j = 0; j < 4; ++j) {
        const h4v* pj = plane + (size_t)j * BHW;
        h8v rA = *(const h8v*)(pj + oA);
        h8v rB = *(const h8v*)(pj + oB);

        h4v tA = lo4(rA), uA = hi4(rA);
        h4v tB = lo4(rB), uB = hi4(rB);

        // packed fp16 bilinear: x-lerp both rows, then y-lerp
        h4v ax = tA + wxv * (uA - tA);
        h4v bx = tB + wxv * (uB - tB);
        h4v cy = ax + wyv * (bx - ax);   // {xs0, xs1, ss0, ss1}

        h2v xs2; xs2[0] = cy[0]; xs2[1] = cy[1];
        h2v ss2; ss2[0] = cy[2]; ss2[1] = cy[3];

        // dw = 0.5 + y*P(y^2), y = max(2 - 40|xs-xnc|, -2)
        h2v del  = xs2 - xnc2[j];
        h2v absd = __builtin_elementwise_max(del, -del);
        h2v y2   = __builtin_elementwise_max(two + n40 * absd, ntwo);
        h2v u2   = y2 * y2;
        h2v P    = c2v + u2 * c3v;
        P        = c1v + u2 * P;
        P        = c0v + u2 * P;
        h2v dw2  = halfv + y2 * P;
        h2v pr   = dw2 * ss2;

        acc[2 * j]     = fmaf((float)pr[0], fw, acc[2 * j]);
        acc[2 * j + 1] = fmaf((float)pr[1], fw, acc[2 * j + 1]);
    }
}

// ---------------- Kernel 2: neighbor gather + sigmoid kernel + aggregate ----------------
// NEIGHBORS SPLIT ACROSS WAVE-PAIRS: block = 256 threads over 128 pixels.
// Threads 0-127 (waves 0,1) handle n=0..4; threads 128-255 (waves 2,3) handle
// n=5..8 for the same 128 pixels. Every wave keeps single-n coherent gather
// streams; per-wave work halves and resident waves/SIMD roughly doubles,
// hiding the grid->tap latency chain that capped rounds 12-15. Partial sums
// combine via conflict-free LDS red[D][128] + one barrier; half 0 writes.
// GRID: B*HW/128 = 2560 blocks (round 16 launched 10240 -> OOB fault).
__global__ __launch_bounds__(256) void k_aggregate(
    const float* __restrict__ grid,      // [B, N*H, W, 2]
    const float* __restrict__ fweight,   // [B, N, H, W]
    const h4v* __restrict__ plane,       // [4][B*HW]
    float* __restrict__ out)             // [B,D,H,W]
{
    __shared__ float red[D_][128];

    int p    = threadIdx.x & 127;        // pixel slot in block
    int half = threadIdx.x >> 7;         // 0: n=0..4, 1: n=5..8
    int idx  = swz_band(blockIdx.x, 320) * 128 + p;   // b*HW + pix
    int b    = idx / HW;
    int pix  = idx % HW;
    int h    = pix / W_;
    int wq   = pix % W_;

    const float2* gpx = (const float2*)grid + (size_t)b * (N_ * H_) * W_ + (size_t)h * W_ + wq;
    const float*  fpx = fweight + (size_t)b * N_ * HW + (size_t)h * W_ + wq;

    // ---- center xnorm pair per plane ----
    h2v xnc2[4];
#pragma unroll
    for (int j = 0; j < 4; ++j) {
        h4v v = plane[(size_t)j * BHW + idx];
        h2v q; q[0] = v[0]; q[1] = v[1];
        xnc2[j] = q;
    }

    float acc[D_];
#pragma unroll
    for (int d = 0; d < D_; ++d) acc[d] = 0.0f;

    const int bbase = b * HW;

    if (half == 0) {
#pragma unroll
        for (int n = 0; n < 5; ++n) {
            float2 g  = gpx[(size_t)n * (H_ * W_)];
            float  fw = fpx[(size_t)n * HW];
            neighbor_accum(plane, bbase, g, fw, xnc2, acc);
        }
    } else {
#pragma unroll
        for (int n = 5; n < N_; ++n) {
            float2 g  = gpx[(size_t)n * (H_ * W_)];
            float  fw = fpx[(size_t)n * HW];
            neighbor_accum(plane, bbase, g, fw, xnc2, acc);
        }
        // stash half-1 partials
#pragma unroll
        for (int d = 0; d < D_; ++d) red[d][p] = acc[d];
    }

    __syncthreads();

    if (half == 0) {
#pragma unroll
        for (int d = 0; d < D_; ++d)
            out[(b * D_ + d) * HW + pix] = acc[d] + red[d][p];
    }
}

extern "C" void kernel_launch(void* const* d_in, const int* in_sizes, int n_in,
                              void* d_out, int out_size, void* d_ws, size_t ws_size,
                              hipStream_t stream) {
    const float* cost    = (const float*)d_in[0];
    const float* dsamp   = (const float*)d_in[1];
    const float* dmin    = (const float*)d_in[2];
    const float* dmax    = (const float*)d_in[3];
    const float* grid    = (const float*)d_in[4];
    const float* fweight = (const float*)d_in[5];
    const float* w0 = (const float*)d_in[6];
    const float* g0 = (const float*)d_in[7];
    const float* b0 = (const float*)d_in[8];
    const float* m0 = (const float*)d_in[9];
    const float* v0 = (const float*)d_in[10];
    const float* w1 = (const float*)d_in[11];
    const float* g1 = (const float*)d_in[12];
    const float* b1 = (const float*)d_in[13];
    const float* m1 = (const float*)d_in[14];
    const float* v1 = (const float*)d_in[15];
    const float* w2 = (const float*)d_in[16];
    const float* b2 = (const float*)d_in[17];
    float* out = (float*)d_out;

    float* ws    = (float*)d_ws;
    h4v*   plane = (h4v*)(ws + WS_PAIR_OFF);

    k_setup<<<1, 64, 0, stream>>>(dmin, dmax,
                                  w0, g0, b0, m0, v0,
                                  w1, g1, b1, m1, v1,
                                  w2, b2, ws);

    // k1: 5120 blocks over (pixel, depth-pair); k2: 2560 blocks over
    // 128-pixel groups (x2 neighbor-halves inside the block). Both map
    // pixel p -> XCD p/40960 (producer/consumer L2 affinity).
    k_s_xnorm<<<5120, 256, 0, stream>>>(cost, dsamp, ws, plane);
    k_aggregate<<<2560, 256, 0, stream>>>(grid, fweight, plane, out);
}